// Round 8
// baseline (1162.424 us; speedup 1.0000x reference)
//
#include <hip/hip_runtime.h>
#include <cstdint>

#define TT 2048
#define NH 15

typedef _Float16 half8 __attribute__((ext_vector_type(8)));
typedef float f32x4 __attribute__((ext_vector_type(4)));
typedef int int4v __attribute__((ext_vector_type(4)));

#define EXP2(x) __builtin_amdgcn_exp2f(x)
#define RCP(x) __builtin_amdgcn_rcpf(x)
#define BPERM(addr, v) __builtin_amdgcn_ds_bpermute((addr), (v))
#define PKRTZ_I(a, b) __builtin_bit_cast(int, __builtin_amdgcn_cvt_pkrtz((a), (b)))
#define MFMA16(A, B, C) __builtin_amdgcn_mfma_f32_16x16x32_f16((A), (B), (C), 0, 0, 0)
#define F16LO(x) ((short)(PKRTZ_I((x), 0.0f) & 0xFFFF))

// Rational-fused gates on PRE-SCALED mfma outputs (R7-validated):
//   d0=-zi*log2e, d1=-zf*log2e, d2=+2*zg*log2e, d3=-zo*log2e
//   c' = [c*(1+ui)(sg+1) + (1+uf)(sg-1)] / [(1+uf)(1+ui)(sg+1)]
//   h  = (sc-1) / ((1+uo)(sc+1)),  sc = e^{2c'}
// 5 exp2 + 2 rcp per GATES (exact-math floor).
#define GATES_RAT(d0, d1, d2, d3, cref, hout) { \
    const float ui_ = EXP2(d0); \
    const float uf_ = EXP2(d1); \
    const float sg_ = EXP2(d2); \
    const float uo_ = EXP2(d3); \
    const float a_  = 1.0f + ui_; \
    const float b_  = 1.0f + sg_; \
    const float e_  = 1.0f + uf_; \
    const float ab_ = a_ * b_; \
    const float num_ = fmaf((cref), ab_, e_ * (sg_ - 1.0f)); \
    (cref) = num_ * RCP(ab_ * e_); \
    const float sc_ = EXP2((cref) * 2.8853900817779268f); \
    (hout) = (sc_ - 1.0f) * RCP((1.0f + uo_) * (sc_ + 1.0f)); }

// raw barrier: LDS-ordering only (no vmcnt drain of x-prefetch / out-stores)
#define LDS_BAR() { asm volatile("s_waitcnt lgkmcnt(0)" ::: "memory"); \
                    __builtin_amdgcn_s_barrier(); }

// 4-wave trans-balanced cell split, layer-wavefront staggered MFMA LSTM.
// Block = 256 threads = 4 waves, one 16-element batch tile; 512 blocks
// -> 2048 waves = 2 waves/SIMD on all 1024 SIMDs (R7 ran 1/SIMD with
// ~475 cy/step of uncovered stall; per-SIMD trans work is conserved, so
// the 2nd wave converts stall into issue).
//   w0: cell1 r0,r1,r2            (4 MFMA)
//   w1: cell1 r3 + cell2 r0,r1    (8 MFMA)
//   w2: cell2 r2,r3 + cell3 r0    (8 MFMA)
//   w3: cell3 r1,r2,r3 + head     (5 MFMA)
// Each wave = exactly 3 GATES (21 trans) -> perfectly trans-balanced.
// MFMA duplication rides the idle matrix pipe (MfmaUtil ~11%).
//
// LDS exchange words [parity][word][lane] (lag-1, 1 barrier/step):
//   W0=pk(h1r0,h1r1)<-w0   W1=pk(h1r2,h1r3)<-w0.lo+w1.hi (b16 halves)
//   W2=pk(h2r0,h2r1)<-w1   W3v=q3?(h2r2,bias):(h2r2,h2r3)<-w2
//   W4=pk(h3r0,h3r1)<-w2.lo+w3.hi                W5v=q3?(h3r2,g3):(h3r2,h3r3)<-w3
// B1={W0,W1|x@q3hi,0,bias1@q3}; B2={W0,W1,W2,W3v}; B3={W2,W3v,W4,W5v};
// head = extra MFMA on B3 (w_lin over own-slots of row m=0, b_lin at k31).
// q3-hi of in-side words is don't-care for cells 2/3 (zero A columns), so
// the bias variants double as plain words. Half-word (b16) LDS writes are
// barrier-separated from all conflicting accesses.
// Warmup: zero-init LDS => zero fragments => states exactly 0 for tau<0;
// only cell3's bias (W5v hi) is gated at iter 0. Tail iters never stored.
__global__ __launch_bounds__(256) __attribute__((amdgpu_waves_per_eu(2)))
void lstm3_split4(const float* __restrict__ input,
                  const float* __restrict__ w_ih1, const float* __restrict__ w_hh1,
                  const float* __restrict__ b_ih1, const float* __restrict__ b_hh1,
                  const float* __restrict__ w_ih2, const float* __restrict__ w_hh2,
                  const float* __restrict__ b_ih2, const float* __restrict__ b_hh2,
                  const float* __restrict__ w_ih3, const float* __restrict__ w_hh3,
                  const float* __restrict__ b_ih3, const float* __restrict__ b_hh3,
                  const float* __restrict__ w_lin, const float* __restrict__ b_lin,
                  float* __restrict__ out)
{
    __shared__ int lds[2][6][64];     // 3 KiB

    const int tid = threadIdx.x;
    const int w = tid >> 6;           // wave role 0..3
    const int lane = tid & 63;
    const int n = lane & 15;          // element col AND A-row m
    const int q = lane >> 4;          // quad
    const bool q3 = (q == 3);

    for (int k = tid; k < 2 * 6 * 64; k += 256) ((int*)lds)[k] = 0;
    __syncthreads();

    const f32x4 z4 = {0.f, 0.f, 0.f, 0.f};
    // gate order i,f,g,o: sigmoid rows scaled by -log2e, tanh row by +2log2e
    const float SC[4] = {-1.4426950408889634f, -1.4426950408889634f,
                          2.8853900817779268f, -1.4426950408889634f};

    // ---- A-fragment builders (interleaved-K, gate-pre-scaled) ----
    // cell1: in = w_hh1 (u15 = x col -> w_ih1), own = bias only
    // cellX: in = w_ihX, own = w_hhX (u15 = bias)
#define BUILD_A1(a) { \
    _Pragma("unroll") \
    for (int g = 0; g < 4; ++g) { \
        half8 t = {}; \
        _Pragma("unroll") \
        for (int j = 0; j < 8; ++j) { \
            const int u = 4 * q + (j & 3); \
            float v = 0.f; \
            if (n < NH) { \
                const int r = g * NH + n; \
                if (j < 4) v = (u < NH) ? w_hh1[r * NH + u] : w_ih1[r]; \
                else       v = (u < NH) ? 0.f : (b_ih1[r] + b_hh1[r]); \
            } \
            t[j] = (_Float16)(v * SC[g]); \
        } \
        (a)[g] = t; \
    } }
#define BUILD_AX(a, wih, whh, bih, bhh) { \
    _Pragma("unroll") \
    for (int g = 0; g < 4; ++g) { \
        half8 t = {}; \
        _Pragma("unroll") \
        for (int j = 0; j < 8; ++j) { \
            const int u = 4 * q + (j & 3); \
            float v = 0.f; \
            if (n < NH) { \
                const int r = g * NH + n; \
                if (j < 4) v = (u < NH) ? (wih)[r * NH + u] : 0.f; \
                else       v = (u < NH) ? (whh)[r * NH + u] \
                                        : ((bih)[r] + (bhh)[r]); \
            } \
            t[j] = (_Float16)(v * SC[g]); \
        } \
        (a)[g] = t; \
    } }

    const float* xrow = input + (size_t)(blockIdx.x * 16 + n) * TT;
    float* orow = out + (size_t)(blockIdx.x * 16 + n) * TT;

    if (w == 0) {
        // ============ w0: cell1 rows 0,1,2 ============
        half8 a1[4];
        BUILD_A1(a1)
        float c10 = 0.f, c11 = 0.f, c12 = 0.f;
        int W0reg = 0;
        const int b1w3 = q3 ? 0x3C000000 : 0;
        float xtile = xrow[q], xtile_n = xrow[4 + q];
        int xp = PKRTZ_I(0.f, xtile), xp_n = PKRTZ_I(0.f, xtile_n);
        int xvp = BPERM(n * 4, xp);
#pragma unroll 1
        for (int t0 = 0; t0 < TT + 4; t0 += 4) {
#pragma unroll
            for (int ph = 0; ph < 4; ++ph) {
                const int p = (t0 + ph) & 1, pr = p ^ 1;
                const int W1 = lds[pr][1][lane];
                const int xps = (ph == 3) ? xp_n : xp;
                const int xvp_n = BPERM(((ph + 1) & 3) * 64 + n * 4, xps);
                const int b1w1 = q3
                    ? (int)((W1 & 0xFFFF) | (xvp & (int)0xFFFF0000)) : W1;
                const int4v b1 = { W0reg, b1w1, 0, b1w3 };
                const half8 B1 = __builtin_bit_cast(half8, b1);
                f32x4 D0 = MFMA16(a1[0], B1, z4);
                f32x4 D1 = MFMA16(a1[1], B1, z4);
                f32x4 D2 = MFMA16(a1[2], B1, z4);
                f32x4 D3 = MFMA16(a1[3], B1, z4);
                float h0, h1, h2;
                GATES_RAT(D0[0], D1[0], D2[0], D3[0], c10, h0);
                GATES_RAT(D0[1], D1[1], D2[1], D3[1], c11, h1);
                GATES_RAT(D0[2], D1[2], D2[2], D3[2], c12, h2);
                W0reg = PKRTZ_I(h0, h1);
                lds[p][0][lane] = W0reg;
                ((short*)&lds[p][1][lane])[0] = F16LO(h2);   // W1.lo
                xvp = xvp_n;
                LDS_BAR();
            }
            xtile = xtile_n; xp = xp_n;
            const int tn = t0 + 8 + q;
            xtile_n = xrow[(tn < TT) ? tn : q];
            xp_n = PKRTZ_I(0.f, xtile_n);
        }
    } else if (w == 1) {
        // ============ w1: cell1 r3 + cell2 r0,r1 ============
        half8 a1[4], a2[4];
        BUILD_A1(a1)
        BUILD_AX(a2, w_ih2, w_hh2, b_ih2, b_hh2)
        float c13 = 0.f, c20 = 0.f, c21 = 0.f;
        int W2reg = 0;
        const int b1w3 = q3 ? 0x3C000000 : 0;
        float xtile = xrow[q], xtile_n = xrow[4 + q];
        int xp = PKRTZ_I(0.f, xtile), xp_n = PKRTZ_I(0.f, xtile_n);
        int xvp = BPERM(n * 4, xp);
#pragma unroll 1
        for (int t0 = 0; t0 < TT + 4; t0 += 4) {
#pragma unroll
            for (int ph = 0; ph < 4; ++ph) {
                const int p = (t0 + ph) & 1, pr = p ^ 1;
                const int W0 = lds[pr][0][lane];
                const int W1 = lds[pr][1][lane];
                const int W3v = lds[pr][3][lane];
                const int xps = (ph == 3) ? xp_n : xp;
                const int xvp_n = BPERM(((ph + 1) & 3) * 64 + n * 4, xps);
                const int b1w1 = q3
                    ? (int)((W1 & 0xFFFF) | (xvp & (int)0xFFFF0000)) : W1;
                const int4v b1 = { W0, b1w1, 0, b1w3 };
                const int4v b2 = { W0, W1, W2reg, W3v };
                const half8 B1 = __builtin_bit_cast(half8, b1);
                const half8 B2 = __builtin_bit_cast(half8, b2);
                f32x4 E0 = MFMA16(a1[0], B1, z4);
                f32x4 E1 = MFMA16(a1[1], B1, z4);
                f32x4 E2 = MFMA16(a1[2], B1, z4);
                f32x4 E3 = MFMA16(a1[3], B1, z4);
                f32x4 D0 = MFMA16(a2[0], B2, z4);
                f32x4 D1 = MFMA16(a2[1], B2, z4);
                f32x4 D2 = MFMA16(a2[2], B2, z4);
                f32x4 D3 = MFMA16(a2[3], B2, z4);
                float h13, h20, h21;
                GATES_RAT(E0[3], E1[3], E2[3], E3[3], c13, h13);
                GATES_RAT(D0[0], D1[0], D2[0], D3[0], c20, h20);
                GATES_RAT(D0[1], D1[1], D2[1], D3[1], c21, h21);
                ((short*)&lds[p][1][lane])[1] = F16LO(h13);  // W1.hi
                W2reg = PKRTZ_I(h20, h21);
                lds[p][2][lane] = W2reg;
                xvp = xvp_n;
                LDS_BAR();
            }
            xtile = xtile_n; xp = xp_n;
            const int tn = t0 + 8 + q;
            xtile_n = xrow[(tn < TT) ? tn : q];
            xp_n = PKRTZ_I(0.f, xtile_n);
        }
    } else if (w == 2) {
        // ============ w2: cell2 r2,r3 + cell3 r0 ============
        half8 a2[4], a3[4];
        BUILD_AX(a2, w_ih2, w_hh2, b_ih2, b_hh2)
        BUILD_AX(a3, w_ih3, w_hh3, b_ih3, b_hh3)
        float c22 = 0.f, c23 = 0.f, c30 = 0.f;
        int W3vreg = 0;
#pragma unroll 1
        for (int t0 = 0; t0 < TT + 4; t0 += 4) {
#pragma unroll
            for (int ph = 0; ph < 4; ++ph) {
                const int p = (t0 + ph) & 1, pr = p ^ 1;
                const int W0 = lds[pr][0][lane];
                const int W1 = lds[pr][1][lane];
                const int W2 = lds[pr][2][lane];
                const int W4 = lds[pr][4][lane];
                const int W5v = lds[pr][5][lane];
                const int4v b2 = { W0, W1, W2, W3vreg };
                const int4v b3 = { W2, W3vreg, W4, W5v };
                const half8 B2 = __builtin_bit_cast(half8, b2);
                const half8 B3 = __builtin_bit_cast(half8, b3);
                f32x4 D0 = MFMA16(a2[0], B2, z4);
                f32x4 D1 = MFMA16(a2[1], B2, z4);
                f32x4 D2 = MFMA16(a2[2], B2, z4);
                f32x4 D3 = MFMA16(a2[3], B2, z4);
                f32x4 E0 = MFMA16(a3[0], B3, z4);
                f32x4 E1 = MFMA16(a3[1], B3, z4);
                f32x4 E2 = MFMA16(a3[2], B3, z4);
                f32x4 E3 = MFMA16(a3[3], B3, z4);
                float h22, h23, h30;
                GATES_RAT(D0[2], D1[2], D2[2], D3[2], c22, h22);
                GATES_RAT(D0[3], D1[3], D2[3], D3[3], c23, h23);
                GATES_RAT(E0[0], E1[0], E2[0], E3[0], c30, h30);
                const int pk2 = PKRTZ_I(h22, h23);
                W3vreg = q3 ? (int)((pk2 & 0xFFFF) | 0x3C000000) : pk2;
                lds[p][3][lane] = W3vreg;
                ((short*)&lds[p][4][lane])[0] = F16LO(h30);  // W4.lo
                LDS_BAR();
            }
        }
    } else {
        // ============ w3: cell3 r1,r2,r3 + head ============
        half8 a3[4];
        BUILD_AX(a3, w_ih3, w_hh3, b_ih3, b_hh3)
        // head A-frag: row m=0 = w_lin over own-slots, b_lin at k=31
        half8 ah = {};
        if (n == 0) {
#pragma unroll
            for (int j = 4; j < 8; ++j) {
                const int u = 4 * q + (j - 4);
                ah[j] = (_Float16)((u < NH) ? w_lin[u] : b_lin[0]);
            }
        }
        float c31 = 0.f, c32 = 0.f, c33 = 0.f;
        int W5vreg = 0;
        float y4[4] = {0.f, 0.f, 0.f, 0.f};
#pragma unroll 1
        for (int t0 = 0; t0 < TT + 4; t0 += 4) {
#pragma unroll
            for (int ph = 0; ph < 4; ++ph) {
                const int p = (t0 + ph) & 1, pr = p ^ 1;
                const int W2 = lds[pr][2][lane];
                const int W3v = lds[pr][3][lane];
                const int W4 = lds[pr][4][lane];
                const int4v b3 = { W2, W3v, W4, W5vreg };
                const half8 B3 = __builtin_bit_cast(half8, b3);
                f32x4 E0 = MFMA16(a3[0], B3, z4);
                f32x4 E1 = MFMA16(a3[1], B3, z4);
                f32x4 E2 = MFMA16(a3[2], B3, z4);
                f32x4 E3 = MFMA16(a3[3], B3, z4);
                f32x4 Dh = MFMA16(ah, B3, z4);     // y(i-3) in q0/r0
                float h31, h32, h33;
                GATES_RAT(E0[1], E1[1], E2[1], E3[1], c31, h31);
                GATES_RAT(E0[2], E1[2], E2[2], E3[2], c32, h32);
                GATES_RAT(E0[3], E1[3], E2[3], E3[3], c33, h33);
                y4[(ph + 1) & 3] = Dh[0];
                if (ph == 2 && t0 >= 4 && q == 0) {
                    *(f32x4*)(orow + t0 - 4) =
                        (f32x4){y4[0], y4[1], y4[2], y4[3]};
                }
                ((short*)&lds[p][4][lane])[1] = F16LO(h31);  // W4.hi
                const int pk3 = PKRTZ_I(h32, h33);
                const int g3hi = (ph >= 1 || t0 > 0) ? 0x3C000000 : 0;
                W5vreg = q3 ? (int)((pk3 & 0xFFFF) | g3hi) : pk3;
                lds[p][5][lane] = W5vreg;
                LDS_BAR();
            }
        }
    }
#undef BUILD_A1
#undef BUILD_AX
}

extern "C" void kernel_launch(void* const* d_in, const int* in_sizes, int n_in,
                              void* d_out, int out_size, void* d_ws, size_t ws_size,
                              hipStream_t stream) {
    const float* input = (const float*)d_in[0];
    const float* w_ih1 = (const float*)d_in[1];
    const float* w_hh1 = (const float*)d_in[2];
    const float* b_ih1 = (const float*)d_in[3];
    const float* b_hh1 = (const float*)d_in[4];
    const float* w_ih2 = (const float*)d_in[5];
    const float* w_hh2 = (const float*)d_in[6];
    const float* b_ih2 = (const float*)d_in[7];
    const float* b_hh2 = (const float*)d_in[8];
    const float* w_ih3 = (const float*)d_in[9];
    const float* w_hh3 = (const float*)d_in[10];
    const float* b_ih3 = (const float*)d_in[11];
    const float* b_hh3 = (const float*)d_in[12];
    const float* w_lin = (const float*)d_in[13];
    const float* b_lin = (const float*)d_in[14];
    float* out = (float*)d_out;

    const int B = in_sizes[0] / TT;      // 8192
    const int blocks = B / 16;           // 512 blocks x 4 waves = 2048 waves

    lstm3_split4<<<blocks, 256, 0, stream>>>(
        input, w_ih1, w_hh1, b_ih1, b_hh1,
        w_ih2, w_hh2, b_ih2, b_hh2,
        w_ih3, w_hh3, b_ih3, b_hh3,
        w_lin, b_lin, out);
}

// Round 9
// 1072.726 us; speedup vs baseline: 1.0836x; 1.0836x over previous
//
#include <hip/hip_runtime.h>
#include <cstdint>

#define TT 2048
#define NH 15
#define NIT (TT / 4 + 2)   // 514 iterations of 4 steps

typedef _Float16 half8 __attribute__((ext_vector_type(8)));
typedef float f32x4 __attribute__((ext_vector_type(4)));
typedef int int4v __attribute__((ext_vector_type(4)));

#define EXP2(x) __builtin_amdgcn_exp2f(x)
#define RCP(x) __builtin_amdgcn_rcpf(x)
#define BPERM(addr, v) __builtin_amdgcn_ds_bpermute((addr), (v))
#define PKRTZ_I(a, b) __builtin_bit_cast(int, __builtin_amdgcn_cvt_pkrtz((a), (b)))
#define MFMA16(A, B, C) __builtin_amdgcn_mfma_f32_16x16x32_f16((A), (B), (C), 0, 0, 0)

// Rational-fused gates on PRE-SCALED mfma outputs (R7-validated):
// 5 exp2 + 2 rcp per GATES (exact-math floor).
#define GATES_RAT(d0, d1, d2, d3, cref, hout) { \
    const float ui_ = EXP2(d0); \
    const float uf_ = EXP2(d1); \
    const float sg_ = EXP2(d2); \
    const float uo_ = EXP2(d3); \
    const float a_  = 1.0f + ui_; \
    const float b_  = 1.0f + sg_; \
    const float e_  = 1.0f + uf_; \
    const float ab_ = a_ * b_; \
    const float num_ = fmaf((cref), ab_, e_ * (sg_ - 1.0f)); \
    (cref) = num_ * RCP(ab_ * e_); \
    const float sc_ = EXP2((cref) * 2.8853900817779268f); \
    (hout) = (sc_ - 1.0f) * RCP((1.0f + uo_) * (sc_ + 1.0f)); }

// raw barrier: LDS-ordering only (no vmcnt drain of x-prefetch / out-stores)
#define LDS_BAR() { asm volatile("s_waitcnt lgkmcnt(0)" ::: "memory"); \
                    __builtin_amdgcn_s_barrier(); }

// 3-wave cell-granular split, 4-steps-per-barrier, deep-staggered MFMA LSTM.
// Block = 192 threads = 3 waves, one 16-element batch tile; 512 blocks ->
// 1536 waves (~1.5/SIMD). R8 lesson: row-splitting duplicates MFMA+assembly;
// cell-granular is the finest duplication-free split. R7 lesson: per-step
// barrier+LDS exposure = ~470cy/step of stall; batching 4 steps per barrier
// amortizes it 4x.
//   w0: cell1, steps [4j .. 4j+3]     (serial in-wave; x input)
//   w1: cell2, steps [4j-4 .. 4j-1]   (reads h1 blocks from iters j-1, j-2)
//   w2: cell3 + head, steps [4j-8 .. 4j-5] (reads h2 block from iter j-1)
// ALL cross-wave deps are cross-iteration -> one barrier + one read burst
// per 4 steps. LDS: 3 rotating slots x 16 words (c1: words 0-7 = step-pack
// pairs; c2: words 8-15). c3 writes nothing (head is in-wave).
//
// Fragment maps (m89-verified): A[m=lane&15][k=(lane>>4)*8+j];
// B[k][n=lane&15]; D col=lane&15, row=(lane>>4)*4+r. Interleaved-K:
// k=8q+j: j<4 "in" unit 4q+j (cell1: u15=x), j>=4 "own" unit 4q+j-4
// (u15 = bias). Head = extra MFMA row (w_lin on own-slots, b_lin at k31);
// head frag s yields y(tau_s - 1); frags s=1..3 + one own-side-only extra
// frag give y[4j-8 .. 4j-5] -> aligned float4 store per iteration.
// Warmup: zero-init LDS + per-iteration-uniform bias gating (c2: j>=1,
// c3: j>=2, kept-variant gates shifted +1) keeps all tau<0 states exactly 0.
// Tail iters compute garbage never stored. Dataflow values identical to R7.
__global__ __launch_bounds__(192) __attribute__((amdgpu_waves_per_eu(2)))
void lstm3_pipe(const float* __restrict__ input,
                const float* __restrict__ w_ih1, const float* __restrict__ w_hh1,
                const float* __restrict__ b_ih1, const float* __restrict__ b_hh1,
                const float* __restrict__ w_ih2, const float* __restrict__ w_hh2,
                const float* __restrict__ b_ih2, const float* __restrict__ b_hh2,
                const float* __restrict__ w_ih3, const float* __restrict__ w_hh3,
                const float* __restrict__ b_ih3, const float* __restrict__ b_hh3,
                const float* __restrict__ w_lin, const float* __restrict__ b_lin,
                float* __restrict__ out)
{
    __shared__ int lds[3][16][64];    // 12 KiB; [slot][word][lane]

    const int tid = threadIdx.x;
    const int w = tid >> 6;           // wave role 0..2
    const int lane = tid & 63;
    const int n = lane & 15;          // element col AND A-row m
    const int q = lane >> 4;          // quad
    const bool q3 = (q == 3);

    for (int k = tid; k < 3 * 16 * 64; k += 192) ((int*)lds)[k] = 0;
    __syncthreads();

    const f32x4 z4 = {0.f, 0.f, 0.f, 0.f};
    // gate order i,f,g,o: sigmoid rows scaled by -log2e, tanh row by +2log2e
    const float SC[4] = {-1.4426950408889634f, -1.4426950408889634f,
                          2.8853900817779268f, -1.4426950408889634f};

#define BUILD_A1(a) { \
    _Pragma("unroll") \
    for (int g = 0; g < 4; ++g) { \
        half8 t = {}; \
        _Pragma("unroll") \
        for (int jj = 0; jj < 8; ++jj) { \
            const int u = 4 * q + (jj & 3); \
            float v = 0.f; \
            if (n < NH) { \
                const int r = g * NH + n; \
                if (jj < 4) v = (u < NH) ? w_hh1[r * NH + u] : w_ih1[r]; \
                else        v = (u < NH) ? 0.f : (b_ih1[r] + b_hh1[r]); \
            } \
            t[jj] = (_Float16)(v * SC[g]); \
        } \
        (a)[g] = t; \
    } }
#define BUILD_AX(a, wih, whh, bih, bhh) { \
    _Pragma("unroll") \
    for (int g = 0; g < 4; ++g) { \
        half8 t = {}; \
        _Pragma("unroll") \
        for (int jj = 0; jj < 8; ++jj) { \
            const int u = 4 * q + (jj & 3); \
            float v = 0.f; \
            if (n < NH) { \
                const int r = g * NH + n; \
                if (jj < 4) v = (u < NH) ? (wih)[r * NH + u] : 0.f; \
                else        v = (u < NH) ? (whh)[r * NH + u] \
                                         : ((bih)[r] + (bhh)[r]); \
            } \
            t[jj] = (_Float16)(v * SC[g]); \
        } \
        (a)[g] = t; \
    } }

    const size_t row = (size_t)(blockIdx.x * 16 + n);

    // rotating slot indices: s0 = j%3 (write), s1 = (j-1)%3, s2 = (j-2)%3
    int s0 = 0, s1 = 2, s2 = 1;

    if (w == 0) {
        // ================= cell1: steps 4j .. 4j+3 =================
        half8 a1[4];
        BUILD_A1(a1)
        int p01 = 0, p23 = 0;         // packed h1(t-1)
        float cf[4] = {0.f, 0.f, 0.f, 0.f};
        const int bw3 = q3 ? 0x3C000000 : 0;
        const float* xrow = input + row * TT;
        float xt = xrow[q];
        int xp = PKRTZ_I(0.f, xt);    // hi16 = f16(x(4j+q))
        const int n4 = n * 4;
#pragma unroll 1
        for (int j = 0; j < NIT; ++j) {
            const int xv0 = BPERM(n4, xp);
            const int xv1 = BPERM(n4 + 64, xp);
            const int xv2 = BPERM(n4 + 128, xp);
            const int xv3 = BPERM(n4 + 192, xp);
            const int tn = 4 * j + 4 + q;
            const float xtn = xrow[(tn < TT) ? tn : q];   // prefetch next tile
#define C1STEP(xv, s) { \
            const int d1 = q3 ? (int)((p23 & 0xFFFF) | ((xv) & (int)0xFFFF0000)) \
                              : p23; \
            const int4v bi = { p01, d1, 0, bw3 }; \
            const half8 Bf = __builtin_bit_cast(half8, bi); \
            const f32x4 D0 = MFMA16(a1[0], Bf, z4); \
            const f32x4 D1 = MFMA16(a1[1], Bf, z4); \
            const f32x4 D2 = MFMA16(a1[2], Bf, z4); \
            const f32x4 D3 = MFMA16(a1[3], Bf, z4); \
            float h0, h1, h2, h3; \
            GATES_RAT(D0[0], D1[0], D2[0], D3[0], cf[0], h0); \
            GATES_RAT(D0[1], D1[1], D2[1], D3[1], cf[1], h1); \
            GATES_RAT(D0[2], D1[2], D2[2], D3[2], cf[2], h2); \
            GATES_RAT(D0[3], D1[3], D2[3], D3[3], cf[3], h3); \
            p01 = PKRTZ_I(h0, h1); p23 = PKRTZ_I(h2, h3); \
            lds[s0][2 * (s)][lane] = p01; \
            lds[s0][2 * (s) + 1][lane] = p23; }
            C1STEP(xv0, 0)
            C1STEP(xv1, 1)
            C1STEP(xv2, 2)
            C1STEP(xv3, 3)
#undef C1STEP
            xp = PKRTZ_I(0.f, xtn);
            const int t_ = s0; s0 = s2; s2 = s1; s1 = t_;
            LDS_BAR();
        }
    } else if (w == 1) {
        // ================= cell2: steps 4j-4 .. 4j-1 =================
        half8 a2[4];
        BUILD_AX(a2, w_ih2, w_hh2, b_ih2, b_hh2)
        int p01 = 0, p23v = 0;        // packed h2(t-1); p23v = q3 bias variant
        float cf[4] = {0.f, 0.f, 0.f, 0.f};
#pragma unroll 1
        for (int j = 0; j < NIT; ++j) {
            // h1(t-1) packs: step0 from iter j-2 (its last step), 1-3 from j-1
            const int rA0 = lds[s2][6][lane], rB0 = lds[s2][7][lane];
            const int rA1 = lds[s1][0][lane], rB1 = lds[s1][1][lane];
            const int rA2 = lds[s1][2][lane], rB2 = lds[s1][3][lane];
            const int rA3 = lds[s1][4][lane], rB3 = lds[s1][5][lane];
            const int hiIn = (j >= 1) ? 0x3C000000 : 0;
#define C2STEP(rA, rB, s, HI) { \
            const int4v bi = { (rA), (rB), p01, p23v }; \
            const half8 Bf = __builtin_bit_cast(half8, bi); \
            const f32x4 D0 = MFMA16(a2[0], Bf, z4); \
            const f32x4 D1 = MFMA16(a2[1], Bf, z4); \
            const f32x4 D2 = MFMA16(a2[2], Bf, z4); \
            const f32x4 D3 = MFMA16(a2[3], Bf, z4); \
            float h0, h1, h2, h3; \
            GATES_RAT(D0[0], D1[0], D2[0], D3[0], cf[0], h0); \
            GATES_RAT(D0[1], D1[1], D2[1], D3[1], cf[1], h1); \
            GATES_RAT(D0[2], D1[2], D2[2], D3[2], cf[2], h2); \
            GATES_RAT(D0[3], D1[3], D2[3], D3[3], cf[3], h3); \
            p01 = PKRTZ_I(h0, h1); \
            const int pk23 = PKRTZ_I(h2, h3); \
            lds[s0][8 + 2 * (s)][lane] = p01; \
            lds[s0][9 + 2 * (s)][lane] = pk23; \
            p23v = q3 ? (int)((pk23 & 0xFFFF) | (HI)) : pk23; }
            C2STEP(rA0, rB0, 0, hiIn)
            C2STEP(rA1, rB1, 1, hiIn)
            C2STEP(rA2, rB2, 2, hiIn)
            C2STEP(rA3, rB3, 3, 0x3C000000)   // next iter's step0: t=4j>=0 always
#undef C2STEP
            const int t_ = s0; s0 = s2; s2 = s1; s1 = t_;
            LDS_BAR();
        }
    } else {
        // ============ cell3 + head: steps 4j-8 .. 4j-5 ============
        half8 a3[4];
        BUILD_AX(a3, w_ih3, w_hh3, b_ih3, b_hh3)
        // head A-frag: row m=0 = w_lin over own-slots, b_lin at k=31 (unscaled)
        half8 ah = {};
        if (n == 0) {
#pragma unroll
            for (int jj = 4; jj < 8; ++jj) {
                const int u = 4 * q + (jj - 4);
                ah[jj] = (_Float16)((u < NH) ? w_lin[u] : b_lin[0]);
            }
        }
        int p01 = 0, p23v = 0;        // packed h3(t-1); p23v = q3 bias variant
        float cf[4] = {0.f, 0.f, 0.f, 0.f};
        float* orow = out + row * TT;
#pragma unroll 1
        for (int j = 0; j < NIT; ++j) {
            // h2 packs for steps 4j-8..4j-5 = c2's iter j-1 block
            const int rA0 = lds[s1][8][lane],  rB0 = lds[s1][9][lane];
            const int rA1 = lds[s1][10][lane], rB1 = lds[s1][11][lane];
            const int rA2 = lds[s1][12][lane], rB2 = lds[s1][13][lane];
            const int rA3 = lds[s1][14][lane], rB3 = lds[s1][15][lane];
            const int hiIn = (j >= 2) ? 0x3C000000 : 0;
            float y0 = 0.f, y1 = 0.f, y2 = 0.f, y3 = 0.f;
#define C3STEP(rA, rB, HI, HEADY) { \
            const int4v bi = { (rA), (rB), p01, p23v }; \
            const half8 Bf = __builtin_bit_cast(half8, bi); \
            HEADY \
            const f32x4 D0 = MFMA16(a3[0], Bf, z4); \
            const f32x4 D1 = MFMA16(a3[1], Bf, z4); \
            const f32x4 D2 = MFMA16(a3[2], Bf, z4); \
            const f32x4 D3 = MFMA16(a3[3], Bf, z4); \
            float h0, h1, h2, h3; \
            GATES_RAT(D0[0], D1[0], D2[0], D3[0], cf[0], h0); \
            GATES_RAT(D0[1], D1[1], D2[1], D3[1], cf[1], h1); \
            GATES_RAT(D0[2], D1[2], D2[2], D3[2], cf[2], h2); \
            GATES_RAT(D0[3], D1[3], D2[3], D3[3], cf[3], h3); \
            p01 = PKRTZ_I(h0, h1); \
            const int pk23 = PKRTZ_I(h2, h3); \
            p23v = q3 ? (int)((pk23 & 0xFFFF) | (HI)) : pk23; }
            C3STEP(rA0, rB0, hiIn, )
            C3STEP(rA1, rB1, hiIn, y0 = MFMA16(ah, Bf, z4)[0];)
            C3STEP(rA2, rB2, hiIn, y1 = MFMA16(ah, Bf, z4)[0];)
            // step3 variant gates next iter's step0: t = 4(j+1)-8 >= 0 <=> j>=1
            {
                const int hiK = (j >= 1) ? 0x3C000000 : 0;
                C3STEP(rA3, rB3, hiK, y2 = MFMA16(ah, Bf, z4)[0];)
            }
#undef C3STEP
            // extra own-side-only frag -> y(4j-5) from post-update h3
            {
                const int4v be = { 0, 0, p01, p23v };
                const half8 Be = __builtin_bit_cast(half8, be);
                y3 = MFMA16(ah, Be, z4)[0];
            }
            if (q == 0 && j >= 2)
                *(f32x4*)(orow + 4 * j - 8) = (f32x4){y0, y1, y2, y3};
            const int t_ = s0; s0 = s2; s2 = s1; s1 = t_;
            LDS_BAR();
        }
    }
#undef BUILD_A1
#undef BUILD_AX
}

extern "C" void kernel_launch(void* const* d_in, const int* in_sizes, int n_in,
                              void* d_out, int out_size, void* d_ws, size_t ws_size,
                              hipStream_t stream) {
    const float* input = (const float*)d_in[0];
    const float* w_ih1 = (const float*)d_in[1];
    const float* w_hh1 = (const float*)d_in[2];
    const float* b_ih1 = (const float*)d_in[3];
    const float* b_hh1 = (const float*)d_in[4];
    const float* w_ih2 = (const float*)d_in[5];
    const float* w_hh2 = (const float*)d_in[6];
    const float* b_ih2 = (const float*)d_in[7];
    const float* b_hh2 = (const float*)d_in[8];
    const float* w_ih3 = (const float*)d_in[9];
    const float* w_hh3 = (const float*)d_in[10];
    const float* b_ih3 = (const float*)d_in[11];
    const float* b_hh3 = (const float*)d_in[12];
    const float* w_lin = (const float*)d_in[13];
    const float* b_lin = (const float*)d_in[14];
    float* out = (float*)d_out;

    const int B = in_sizes[0] / TT;      // 8192
    const int blocks = B / 16;           // 512 blocks x 3 waves = 1536 waves

    lstm3_pipe<<<blocks, 192, 0, stream>>>(
        input, w_ih1, w_hh1, b_ih1, b_hh1,
        w_ih2, w_hh2, b_ih2, b_hh2,
        w_ih3, w_hh3, b_ih3, b_hh3,
        w_lin, b_lin, out);
}